// Round 1
// baseline (775.732 us; speedup 1.0000x reference)
//
#include <hip/hip_runtime.h>
#include <math.h>

// Problem shape (fixed by the reference): B=32, T=4096, H=1024, fp32.
#define B_ 32
#define T_ 4096
#define H_ 1024
#define H4_ 256          // H_/4 float4 per (b,t) row
#define NCHUNK_ 64       // t-chunks for context partials (T_/NCHUNK_ = 64 t per chunk)
#define TPC_ 64          // t per chunk

// ---------------------------------------------------------------------------
// Kernel 1: scores[t] = sum_{b,h} s[b,h] * eh[b,t,h]
// One block per t. 256 threads, each handles 32 float4 of the 8192-float4
// (b,h) slab. decoder_state is 128 KiB -> L2-resident across blocks.
// ---------------------------------------------------------------------------
__global__ __launch_bounds__(256) void scores_kernel(
    const float4* __restrict__ s4, const float4* __restrict__ eh4,
    float* __restrict__ scores)
{
    const int t   = blockIdx.x;
    const int tid = threadIdx.x;

    float acc = 0.f;
#pragma unroll 8
    for (int k = 0; k < 32; ++k) {
        int idx4 = tid + k * 256;           // [0, 8192)
        int b    = idx4 >> 8;               // idx4 / 256
        int h4   = idx4 & 255;
        float4 e  = eh4[((size_t)b * T_ + t) * H4_ + h4];
        float4 sv = s4[idx4];
        acc += e.x * sv.x + e.y * sv.y + e.z * sv.z + e.w * sv.w;
    }

    // wave(64) shuffle reduce, then cross-wave via LDS
    for (int off = 32; off > 0; off >>= 1)
        acc += __shfl_down(acc, off, 64);
    __shared__ float red[4];
    if ((tid & 63) == 0) red[tid >> 6] = acc;
    __syncthreads();
    if (tid == 0) scores[t] = red[0] + red[1] + red[2] + red[3];
}

// ---------------------------------------------------------------------------
// Kernel 2: dist = softmax(scores) over T.  One block, 256 threads x 16 vals.
// ---------------------------------------------------------------------------
__global__ __launch_bounds__(256) void softmax_kernel(
    const float* __restrict__ scores, float* __restrict__ dist)
{
    const int tid = threadIdx.x;
    __shared__ float redm[4];
    __shared__ float reds[4];

    float v[16];
    float m = -INFINITY;
#pragma unroll
    for (int k = 0; k < 16; ++k) {
        v[k] = scores[tid + k * 256];
        m = fmaxf(m, v[k]);
    }
    for (int off = 32; off > 0; off >>= 1)
        m = fmaxf(m, __shfl_down(m, off, 64));
    if ((tid & 63) == 0) redm[tid >> 6] = m;
    __syncthreads();
    const float M = fmaxf(fmaxf(redm[0], redm[1]), fmaxf(redm[2], redm[3]));

    float e[16];
    float sum = 0.f;
#pragma unroll
    for (int k = 0; k < 16; ++k) {
        e[k] = expf(v[k] - M);
        sum += e[k];
    }
    for (int off = 32; off > 0; off >>= 1)
        sum += __shfl_down(sum, off, 64);
    if ((tid & 63) == 0) reds[tid >> 6] = sum;
    __syncthreads();
    const float L = reds[0] + reds[1] + reds[2] + reds[3];
    const float inv = 1.f / L;
#pragma unroll
    for (int k = 0; k < 16; ++k)
        dist[tid + k * 256] = e[k] * inv;
}

// ---------------------------------------------------------------------------
// Kernel 3: partial context. grid = (NCHUNK_, B_). Each block accumulates
// TPC_ consecutive t rows (contiguous 4 KiB each, fully coalesced) into one
// float4 per thread, written to partials (no atomics; ws is poisoned 0xAA).
// ---------------------------------------------------------------------------
__global__ __launch_bounds__(256) void context_kernel(
    const float4* __restrict__ eh4, const float* __restrict__ dist,
    float4* __restrict__ part4)
{
    const int chunk = blockIdx.x;   // [0, NCHUNK_)
    const int b     = blockIdx.y;   // [0, B_)
    const int tid   = threadIdx.x;  // h4 index

    const float4* base = eh4 + ((size_t)b * T_ + (size_t)chunk * TPC_) * H4_ + tid;
    const float*  wbase = dist + chunk * TPC_;

    float4 acc = make_float4(0.f, 0.f, 0.f, 0.f);
#pragma unroll 8
    for (int i = 0; i < TPC_; ++i) {
        float  w = wbase[i];          // uniform across block -> scalar load
        float4 e = base[(size_t)i * H4_];
        acc.x += w * e.x;
        acc.y += w * e.y;
        acc.z += w * e.z;
        acc.w += w * e.w;
    }
    part4[((size_t)chunk * B_ + b) * H4_ + tid] = acc;
}

// ---------------------------------------------------------------------------
// Kernel 4: out[b,h] = sum_chunk partial[chunk,b,h].  8192 float4 outputs.
// ---------------------------------------------------------------------------
__global__ __launch_bounds__(256) void reduce_kernel(
    const float4* __restrict__ part4, float4* __restrict__ out4)
{
    const int o4 = blockIdx.x * 256 + threadIdx.x;  // [0, 8192)
    float4 acc = make_float4(0.f, 0.f, 0.f, 0.f);
#pragma unroll 8
    for (int c = 0; c < NCHUNK_; ++c) {
        float4 p = part4[(size_t)c * (B_ * H4_) + o4];
        acc.x += p.x;
        acc.y += p.y;
        acc.z += p.z;
        acc.w += p.w;
    }
    out4[o4] = acc;
}

extern "C" void kernel_launch(void* const* d_in, const int* in_sizes, int n_in,
                              void* d_out, int out_size, void* d_ws, size_t ws_size,
                              hipStream_t stream) {
    const float* s  = (const float*)d_in[0];   // [B, H]
    const float* eh = (const float*)d_in[1];   // [B, T, H]

    float* ws     = (float*)d_ws;
    float* scores = ws;                        // T_ floats
    float* dist   = ws + T_;                   // T_ floats
    float4* part4 = (float4*)(ws + 2 * T_);    // NCHUNK_*B_*H_ floats = 8 MiB

    scores_kernel<<<T_, 256, 0, stream>>>((const float4*)s, (const float4*)eh, scores);
    softmax_kernel<<<1, 256, 0, stream>>>(scores, dist);
    context_kernel<<<dim3(NCHUNK_, B_), 256, 0, stream>>>((const float4*)eh, dist, part4);
    reduce_kernel<<<(B_ * H4_) / 256, 256, 0, stream>>>(part4, (float4*)d_out);
}